// Round 1
// baseline (107.810 us; speedup 1.0000x reference)
//
#include <hip/hip_runtime.h>
#include <hip/hip_fp16.h>

#define S_LEN 1024
#define BATCH 8
#define EMB 512
#define POSD 192
#define NH 8
#define QHD 32
#define PHD 4
#define IN_DIM 544
#define QDIM 256

typedef _Float16 half8 __attribute__((ext_vector_type(8)));
typedef _Float16 half4_t __attribute__((ext_vector_type(4)));
typedef float f32x4 __attribute__((ext_vector_type(4)));

// ---------------- W_in transpose+convert: Wt[n][e] fp16 ----------------
__global__ __launch_bounds__(256) void wconv_kernel(const float* __restrict__ W_in,
                                                    _Float16* __restrict__ Wt) {
  int idx = blockIdx.x * 256 + threadIdx.x;
  if (idx < IN_DIM * EMB) {
    int n = idx >> 9, e = idx & 511;
    Wt[idx] = (_Float16)W_in[(size_t)e * IN_DIM + n];
  }
}

// ---------------- pe = pos_emb @ W_pos  ->  pe16[b][h][n][4] ----------------
__global__ __launch_bounds__(256) void pe_kernel(const float* __restrict__ pos_emb,
                                                 const float* __restrict__ W_pos,
                                                 _Float16* __restrict__ pe16) {
  __shared__ float Wp[POSD * 32];   // 24 KB
  __shared__ float Pr[8][POSD];     // 6 KB
  const int b = blockIdx.y;
  const int nb = blockIdx.x;
  const int tid = threadIdx.x;
  for (int it = tid; it < POSD * 32; it += 256) Wp[it] = W_pos[it];
  for (int it = tid; it < 8 * POSD; it += 256) {
    int nr = it / POSD, e = it % POSD;
    int n = nb * 8 + nr;
    Pr[nr][e] = (n < 2 * S_LEN - 1) ? pos_emb[((size_t)b * (2 * S_LEN - 1) + n) * POSD + e] : 0.f;
  }
  __syncthreads();
  const int nr = tid >> 5, hd = tid & 31;
  const int n = nb * 8 + nr;
  if (n < 2 * S_LEN - 1) {
    float acc = 0.f;
    #pragma unroll 8
    for (int e = 0; e < POSD; ++e) acc += Pr[nr][e] * Wp[e * 32 + hd];
    int h = hd >> 2, d = hd & 3;
    pe16[(((size_t)(b * NH + h)) * (2 * S_LEN - 1) + n) * PHD + d] = (_Float16)acc;
  }
}

// ---------------- proj = x @ W_in + b  ->  q16/k16/p16 [b][h][s][d] fp16 -------
__global__ __launch_bounds__(256) void proj_kernel(const float* __restrict__ x,
                                                   const _Float16* __restrict__ Wt,
                                                   const float* __restrict__ bias,
                                                   _Float16* __restrict__ q16,
                                                   _Float16* __restrict__ k16,
                                                   _Float16* __restrict__ p16) {
  __shared__ __align__(16) _Float16 As[64][40];  // pad 40: 80B rows, 16B aligned, 2-way banks
  __shared__ __align__(16) _Float16 Bs[64][40];
  const int m0 = blockIdx.x * 64;
  const int n0 = blockIdx.y * 64;
  const int tid = threadIdx.x;
  const int w = tid >> 6, l = tid & 63, g = l >> 4, lg = l & 15;
  const int wm = w >> 1, wn = w & 1;
  const int srow = tid >> 2, sc = tid & 3;

  f32x4 acc[2][2] = {};

  for (int k0 = 0; k0 < EMB; k0 += 32) {
    // stage A (fp32 -> fp16)
    const float* asrc = x + (size_t)(m0 + srow) * EMB + k0 + sc * 8;
    f32x4 a0 = *(const f32x4*)asrc;
    f32x4 a1 = *(const f32x4*)(asrc + 4);
    half8 ah;
    #pragma unroll
    for (int j = 0; j < 4; ++j) { ah[j] = (_Float16)a0[j]; ah[4 + j] = (_Float16)a1[j]; }
    // stage B
    int nrow = n0 + srow;
    half8 bh8 = {};
    if (nrow < IN_DIM) bh8 = *(const half8*)(Wt + (size_t)nrow * EMB + k0 + sc * 8);
    *(half8*)&As[srow][sc * 8] = ah;
    *(half8*)&Bs[srow][sc * 8] = bh8;
    __syncthreads();
    half8 aF0 = *(const half8*)&As[wm * 32 + lg][g * 8];
    half8 aF1 = *(const half8*)&As[wm * 32 + 16 + lg][g * 8];
    half8 bF0 = *(const half8*)&Bs[wn * 32 + lg][g * 8];
    half8 bF1 = *(const half8*)&Bs[wn * 32 + 16 + lg][g * 8];
    acc[0][0] = __builtin_amdgcn_mfma_f32_16x16x32_f16(aF0, bF0, acc[0][0], 0, 0, 0);
    acc[0][1] = __builtin_amdgcn_mfma_f32_16x16x32_f16(aF0, bF1, acc[0][1], 0, 0, 0);
    acc[1][0] = __builtin_amdgcn_mfma_f32_16x16x32_f16(aF1, bF0, acc[1][0], 0, 0, 0);
    acc[1][1] = __builtin_amdgcn_mfma_f32_16x16x32_f16(aF1, bF1, acc[1][1], 0, 0, 0);
    __syncthreads();
  }

  #pragma unroll
  for (int sm = 0; sm < 2; ++sm)
    #pragma unroll
    for (int sn = 0; sn < 2; ++sn)
      #pragma unroll
      for (int r = 0; r < 4; ++r) {
        int m = m0 + wm * 32 + sm * 16 + 4 * g + r;  // C: row=4*(l>>4)+reg
        int n = n0 + wn * 32 + sn * 16 + lg;         //    col=l&15
        if (n < IN_DIM) {
          float v = acc[sm][sn][r] + bias[n];
          _Float16 hv = (_Float16)v;
          int s = m >> 3, b = m & 7;  // m = s*B + b
          if (n < QDIM) {
            int h = n >> 5, d = n & 31;
            q16[(((size_t)(b * NH + h)) * S_LEN + s) * QHD + d] = hv;
          } else if (n < 2 * QDIM) {
            int n2 = n - QDIM;
            int h = n2 >> 5, d = n2 & 31;
            k16[(((size_t)(b * NH + h)) * S_LEN + s) * QHD + d] = hv;
          } else {
            int n2 = n - 2 * QDIM;
            int h = n2 >> 2, d = n2 & 3;
            p16[(((size_t)(b * NH + h)) * S_LEN + s) * PHD + d] = hv;
          }
        }
      }
}

// ---------------- fused scores + rel + softmax ----------------
// grid: (64 row-blocks, 64 bh). block: 256 = 4 waves, wave w owns cols [w*256, w*256+256)
__global__ __launch_bounds__(256) void attn_kernel(const _Float16* __restrict__ q16,
                                                   const _Float16* __restrict__ k16,
                                                   const _Float16* __restrict__ p16,
                                                   const _Float16* __restrict__ pe16,
                                                   float* __restrict__ out) {
  __shared__ __align__(16) _Float16 peLDS[1040 * 4];  // pe window, 8.3 KB
  __shared__ float wred[2][4][4][4];                  // [max/sum][wave][group][r]
  const int rblk = blockIdx.x;
  const int bh = blockIdx.y;  // = b*NH + h
  const int b = bh >> 3, h = bh & 7;
  const int i0 = rblk * 16;
  const int tid = threadIdx.x;
  const int w = tid >> 6, l = tid & 63, g = l >> 4, lg = l & 15;
  const int nlo = S_LEN - 16 - i0;  // lowest pe index used by this block

  // stage pe window [nlo, nlo+1038] into LDS (8B per n)
  for (int it = tid; it < 1039; it += 256) {
    *(uint2*)&peLDS[it * 4] =
        *(const uint2*)&pe16[((size_t)bh * (2 * S_LEN - 1) + nlo + it) * 4];
  }

  // A fragment (q rows i0..i0+15), row = l&15, k-chunk = 8*(l>>4)
  const _Float16* qbase = q16 + ((size_t)bh * S_LEN + i0) * QHD;
  half8 aF = *(const half8*)(qbase + lg * QHD + g * 8);

  // QK^T: 16 col-tiles, B-frags straight from global (L2-resident)
  const _Float16* kbase = k16 + (size_t)bh * S_LEN * QHD;
  const int jw = w * 256;
  f32x4 acc[16];
  f32x4 zero = {};
  #pragma unroll
  for (int ct = 0; ct < 16; ++ct) {
    int t = jw + ct * 16 + lg;
    half8 bF = *(const half8*)(kbase + (size_t)t * QHD + g * 8);
    acc[ct] = __builtin_amdgcn_mfma_f32_16x16x32_f16(aF, bF, zero, 0, 0, 0);
  }

  // p for this lane's 4 output rows
  float pq[4][4];
  #pragma unroll
  for (int r = 0; r < 4; ++r) {
    half4_t pv = *(const half4_t*)(p16 + ((size_t)bh * S_LEN + i0 + 4 * g + r) * PHD);
    #pragma unroll
    for (int d = 0; d < 4; ++d) pq[r][d] = (float)pv[d];
  }

  __syncthreads();  // peLDS ready

  // rel: acc[ct][r] += p[i] . pe[S-1-i+j]
  #pragma unroll
  for (int ct = 0; ct < 16; ++ct) {
    int j = jw + ct * 16 + lg;
    #pragma unroll
    for (int r = 0; r < 4; ++r) {
      int nl = 15 - 4 * g - r + j;  // (S-1-i+j) - nlo
      half4_t pv = *(const half4_t*)&peLDS[nl * 4];
      acc[ct][r] += pq[r][0] * (float)pv[0] + pq[r][1] * (float)pv[1] +
                    pq[r][2] * (float)pv[2] + pq[r][3] * (float)pv[3];
    }
  }

  // ---- softmax over the full 1024-row: lane-local -> 16-lane group -> cross-wave
  float mx[4], sm[4];
  #pragma unroll
  for (int r = 0; r < 4; ++r) {
    float m = acc[0][r];
    #pragma unroll
    for (int ct = 1; ct < 16; ++ct) m = fmaxf(m, acc[ct][r]);
    #pragma unroll
    for (int off = 1; off < 16; off <<= 1) m = fmaxf(m, __shfl_xor(m, off));
    mx[r] = m;
  }
  if (lg == 0) {
    #pragma unroll
    for (int r = 0; r < 4; ++r) wred[0][w][g][r] = mx[r];
  }
  __syncthreads();
  #pragma unroll
  for (int r = 0; r < 4; ++r) {
    float m = wred[0][0][g][r];
    #pragma unroll
    for (int w2 = 1; w2 < 4; ++w2) m = fmaxf(m, wred[0][w2][g][r]);
    mx[r] = m;
    sm[r] = 0.f;
  }
  #pragma unroll
  for (int ct = 0; ct < 16; ++ct)
    #pragma unroll
    for (int r = 0; r < 4; ++r) {
      float e = __expf(acc[ct][r] - mx[r]);
      acc[ct][r] = e;
      sm[r] += e;
    }
  #pragma unroll
  for (int r = 0; r < 4; ++r) {
    #pragma unroll
    for (int off = 1; off < 16; off <<= 1) sm[r] += __shfl_xor(sm[r], off);
  }
  if (lg == 0) {
    #pragma unroll
    for (int r = 0; r < 4; ++r) wred[1][w][g][r] = sm[r];
  }
  __syncthreads();
  #pragma unroll
  for (int r = 0; r < 4; ++r) {
    float t = 0.f;
    #pragma unroll
    for (int w2 = 0; w2 < 4; ++w2) t += wred[1][w2][g][r];
    sm[r] = 1.0f / t;
  }

  // store normalized probabilities
  float* obase = out + ((size_t)(h * BATCH + b) * S_LEN + i0) * S_LEN;
  #pragma unroll
  for (int ct = 0; ct < 16; ++ct) {
    int j = jw + ct * 16 + lg;
    #pragma unroll
    for (int r = 0; r < 4; ++r) {
      int il = 4 * g + r;
      obase[(size_t)il * S_LEN + j] = acc[ct][r] * sm[r];
    }
  }
}

extern "C" void kernel_launch(void* const* d_in, const int* in_sizes, int n_in,
                              void* d_out, int out_size, void* d_ws, size_t ws_size,
                              hipStream_t stream) {
  const float* x = (const float*)d_in[0];
  const float* pos_emb = (const float*)d_in[1];
  const float* W_in = (const float*)d_in[2];
  const float* b_in = (const float*)d_in[3];
  const float* W_pos = (const float*)d_in[4];
  float* out = (float*)d_out;

  char* ws = (char*)d_ws;
  // workspace layout (all 16B aligned); total ~10.04 MB
  _Float16* Wt = (_Float16*)(ws);                                   // 544*512*2   = 557056
  _Float16* q16 = (_Float16*)(ws + 557056);                         // 64*1024*32*2 = 4194304
  _Float16* k16 = (_Float16*)(ws + 557056 + 4194304);               // 4194304
  _Float16* p16 = (_Float16*)(ws + 557056 + 2 * 4194304);           // 64*1024*4*2 = 524288
  _Float16* pe16 = (_Float16*)(ws + 557056 + 2 * 4194304 + 524288); // 64*2047*4*2 = 1048064

  wconv_kernel<<<dim3((IN_DIM * EMB + 255) / 256), dim3(256), 0, stream>>>(W_in, Wt);
  pe_kernel<<<dim3(256, BATCH), dim3(256), 0, stream>>>(pos_emb, W_pos, pe16);
  proj_kernel<<<dim3(128, 9), dim3(256), 0, stream>>>(x, Wt, b_in, q16, k16, p16);
  attn_kernel<<<dim3(64, 64), dim3(256), 0, stream>>>(q16, k16, p16, pe16, out);
}